// Round 13
// baseline (7874.756 us; speedup 1.0000x reference)
//
#include <hip/hip_runtime.h>
#include <hip/hip_fp16.h>

// Problem constants
#define TT 2048
#define II 1739
#define IIP 1760              // II zero-padded to a multiple of 32 (f16 GEMM K)
#define HN 256
#define H3 768
#define L2E 1.44269504088896f

typedef _Float16 h2 __attribute__((ext_vector_type(2)));
typedef _Float16 h8 __attribute__((ext_vector_type(8)));
typedef float f4 __attribute__((ext_vector_type(4)));

__device__ __forceinline__ float fdot2(h2 a, h2 b, float c) {
#if defined(__has_builtin)
#if __has_builtin(__builtin_amdgcn_fdot2)
  return __builtin_amdgcn_fdot2(a, b, c, false);
#else
  return fmaf((float)a[0], (float)b[0], fmaf((float)a[1], (float)b[1], c));
#endif
#else
  return fmaf((float)a[0], (float)b[0], fmaf((float)a[1], (float)b[1], c));
#endif
}

__device__ __forceinline__ float fast_exp2(float x) {
#if defined(__has_builtin)
#if __has_builtin(__builtin_amdgcn_exp2f)
  return __builtin_amdgcn_exp2f(x);
#else
  return exp2f(x);
#endif
#else
  return exp2f(x);
#endif
}

__device__ __forceinline__ float fast_rcp(float x) {
#if defined(__has_builtin)
#if __has_builtin(__builtin_amdgcn_rcpf)
  return __builtin_amdgcn_rcpf(x);
#else
  return 1.f / x;
#endif
#else
  return 1.f / x;
#endif
}

template <int CTRL>
__device__ __forceinline__ float dpp_qperm(float v) {
  int r = __builtin_amdgcn_update_dpp(0, __builtin_bit_cast(int, v), CTRL, 0xF, 0xF, true);
  return __builtin_bit_cast(float, r);
}

__device__ __forceinline__ h8 h8zero() {
  h8 v;
#pragma unroll
  for (int j = 0; j < 8; ++j) v[j] = (_Float16)0.f;
  return v;
}

// ---------------------------------------------------------------------------
// One-time f32 -> f16 weight conversion (zero-padded K for the W_ih's).
// ---------------------------------------------------------------------------
#define WSEG (768 * IIP)
#define OSEG (II * HN)
__global__ __launch_bounds__(256) void prep_f16(
    const float* __restrict__ We, const float* __restrict__ Wd,
    const float* __restrict__ Wo,
    _Float16* __restrict__ weh, _Float16* __restrict__ wdh,
    _Float16* __restrict__ woh) {
  const int total = 2 * WSEG + OSEG;
  for (int i = blockIdx.x * 256 + threadIdx.x; i < total; i += gridDim.x * 256) {
    if (i < WSEG) {
      int r = i / IIP, k = i - r * IIP;
      weh[i] = (k < II) ? (_Float16)We[(size_t)r * II + k] : (_Float16)0.f;
    } else if (i < 2 * WSEG) {
      int j = i - WSEG;
      int r = j / IIP, k = j - r * IIP;
      wdh[j] = (k < II) ? (_Float16)Wd[(size_t)r * II + k] : (_Float16)0.f;
    } else {
      int j = i - 2 * WSEG;
      woh[j] = (_Float16)Wo[j];
    }
  }
}

// ---------------------------------------------------------------------------
// MFMA f16 GEMM tile body (r11, verified): C = ((A_f32 @ B16^T)+bias)*scale.
// 256 logical threads (fused callers pass tid = threadIdx.x & 255; duplicate
// waves redo identical work -- benign).
// ---------------------------------------------------------------------------
__device__ __forceinline__ void gemm16_tile(
    int tid, int bx, int by,
    const float* __restrict__ A, int K,
    const _Float16* __restrict__ B16, int N, int Kp,
    const float* __restrict__ bias1, const float* __restrict__ bias2, int b2lim,
    float s_lo, float s_hi, int slim,
    float* __restrict__ C,
    _Float16 (*As)[40], _Float16 (*Bs)[40]) {
  const int w = tid >> 6, lane = tid & 63;
  const int col = lane & 15, kg = lane >> 4;
  const int m0 = by * 64, n0 = bx * 64;
  const int srow = tid >> 2, skq = tid & 3;
  f4 acc[4];
#pragma unroll
  for (int m = 0; m < 4; ++m) acc[m] = f4{0.f, 0.f, 0.f, 0.f};

  for (int k0 = 0; k0 < Kp; k0 += 32) {
    const int kk = k0 + skq * 8;
    h8 av = h8zero(), bv = h8zero();
    {
      const float* ap = A + (size_t)(m0 + srow) * K + kk;
      if (kk + 8 <= K) {
        float4 f0, f1;
        __builtin_memcpy(&f0, ap, 16);
        __builtin_memcpy(&f1, ap + 4, 16);
        av[0] = (_Float16)f0.x; av[1] = (_Float16)f0.y;
        av[2] = (_Float16)f0.z; av[3] = (_Float16)f0.w;
        av[4] = (_Float16)f1.x; av[5] = (_Float16)f1.y;
        av[6] = (_Float16)f1.z; av[7] = (_Float16)f1.w;
      } else if (kk < K) {
#pragma unroll
        for (int j = 0; j < 8; ++j)
          if (kk + j < K) av[j] = (_Float16)ap[j];
      }
    }
    {
      const int bn = n0 + srow;
      if (bn < N) bv = *(const h8*)(B16 + (size_t)bn * Kp + kk);
    }
    __syncthreads();
    *(h8*)&As[srow][skq * 8] = av;
    *(h8*)&Bs[srow][skq * 8] = bv;
    __syncthreads();
    h8 b = *(const h8*)&Bs[w * 16 + col][kg * 8];
#pragma unroll
    for (int m = 0; m < 4; ++m) {
      h8 a = *(const h8*)&As[m * 16 + col][kg * 8];
      acc[m] = __builtin_amdgcn_mfma_f32_16x16x32_f16(a, b, acc[m], 0, 0, 0);
    }
  }

  const int n = n0 + w * 16 + col;
  if (n < N) {
    float bb = bias1[n];
    if (bias2 && n < b2lim) bb += bias2[n];
    const float s = (n < slim) ? s_lo : s_hi;
#pragma unroll
    for (int m = 0; m < 4; ++m) {
      const int mr = m0 + m * 16 + kg * 4;
#pragma unroll
      for (int r = 0; r < 4; ++r)
        C[(size_t)(mr + r) * N + n] = (acc[m][r] + bb) * s;
    }
  }
}

__global__ __launch_bounds__(256) void gemm16(
    const float* __restrict__ A, int K,
    const _Float16* __restrict__ B16, int N, int Kp,
    const float* __restrict__ bias1, const float* __restrict__ bias2, int b2lim,
    float s_lo, float s_hi, int slim,
    float* __restrict__ C) {
  __shared__ _Float16 As[64][40];
  __shared__ _Float16 Bs[64][40];
  gemm16_tile(threadIdx.x, blockIdx.x, blockIdx.y, A, K, B16, N, Kp,
              bias1, bias2, b2lim, s_lo, s_hi, slim, C, As, Bs);
}

// ---------------------------------------------------------------------------
// TWO-CU GRU scan. CU b (block b in {0,1}) owns hidden units [128b, 128b+128).
// Per-thread: quad q (= wv*16 + lane>>2) owns unit u = 128b+q; lane kc=lane&3
// covers k-chunk [64kc, 64kc+64) -> 3 rows x 32 fdot2 = 96 fdot2/thread
// (HALF of the 1-CU scan); 96 weight dwords fit the 128-VGPR arch grant.
//
// r12 bug fixes (both were r12-introduced, architecture unchanged):
//  1. LDS h is DOUBLE-BUFFERED again (hbufd[2][160], as in r4-r11).
//     r12's single buffer let a fast wave's publish of h_{t+1} overwrite
//     dwords a slow wave was still reading for step t's matvec.
//  2. The hT_out tail's __shfl is hoisted OUT of the divergent branch
//     (shfl from an exec-masked-off lane is undefined -> henc odd units
//     were garbage).
//
// Per-step h exchange (256 B) via device-scope slots+flags:
//   slots[parity][cu][64] dwords (f16 pairs), flags monotonic.
//   Publish h_{t+1}: relaxed AGENT stores -> __syncthreads (drains vmcnt)
//   -> tid0 release flag = t+2. Fetch h_t: wave 0 spins acquire
//   flag_peer >= t+1, relaxed-loads 64 dwords, writes LDS remote chunks.
//   Publish-before-spin + 2-slot pipeline => deadlock-free; flag-gated
//   overwrite (peer finished step t before we rewrite parity t&1).
// Math is bit-identical to the verified 1-CU scan -> absmax must be
// exactly 0.0078125 (staleness detector).
// ---------------------------------------------------------------------------
__device__ void gru_scan2(
    int b,
    const float* __restrict__ xp, const float* __restrict__ Whh,
    const float* __restrict__ bhh, const float* __restrict__ h0,
    float* __restrict__ hs_out, float* __restrict__ hT_out,
    uint* __restrict__ slots, uint* __restrict__ flags,
    uint* hbufd /* LDS, 2x160 dwords: dbuf, 4 chunks @ stride 40 */) {
  const int tid = threadIdx.x;
  const int lane = tid & 63;
  const int wv = tid >> 6;              // 0..7
  const int kc = lane & 3;              // k-chunk 0..3
  const int q = wv * 16 + (lane >> 2);  // 0..127 local unit index
  const int u = 128 * b + q;            // owned hidden unit
  const int peer = 1 - b;
  uint* myflag = flags + b * 64;        // 256B-separated flag lines
  uint* pflag = flags + peer * 64;

  // Weights: rows {u, u+256, u+512}, k-chunk kc. 96 dwords, pre-scaled.
  h2 wreg[3][32];
#pragma unroll
  for (int gg = 0; gg < 3; ++gg) {
    const float sc = (gg == 2) ? (2.f * L2E) : L2E;
    const float* wr = Whh + (size_t)(gg * HN + u) * HN + kc * 64;
#pragma unroll
    for (int p = 0; p < 32; ++p) {
      float2 f = *(const float2*)(wr + 2 * p);
      wreg[gg][p] = h2{(_Float16)(f.x * sc), (_Float16)(f.y * sc)};
    }
  }

  float hj = h0 ? h0[u] : 0.f;
  const float bhn = bhh[2 * HN + u] * (2.f * L2E);

  // Prologue: local half of h_0 into buf 0 + publish (slot parity 0, flag 1).
  if (tid < 64) {
    const int d = 64 * b + tid;  // global h-dword index of local half
    float a = h0 ? h0[2 * d] : 0.f;
    float c = h0 ? h0[2 * d + 1] : 0.f;
    h2 pv = h2{(_Float16)a, (_Float16)c};
    uint pw = __builtin_bit_cast(uint, pv);
    hbufd[(d >> 5) * 40 + (d & 31)] = pw;
    __hip_atomic_store(&slots[b * 64 + tid], pw, __ATOMIC_RELAXED,
                       __HIP_MEMORY_SCOPE_AGENT);
  }
  __syncthreads();
  if (tid == 0)
    __hip_atomic_store(myflag, 1u, __ATOMIC_RELEASE, __HIP_MEMORY_SCOPE_AGENT);

  for (int t = 0; t < TT; ++t) {
    const int cur = (t & 1) * 160, nxt = ((t + 1) & 1) * 160;
    // Fetch peer's half of h_t into the remote chunks of buf[cur].
    if (wv == 0) {
      while (__hip_atomic_load(pflag, __ATOMIC_ACQUIRE,
                               __HIP_MEMORY_SCOPE_AGENT) < (uint)(t + 1))
        __builtin_amdgcn_s_sleep(1);
      const int dr = 64 * peer + lane;  // global h-dword index of remote half
      uint d = __hip_atomic_load(&slots[(t & 1) * 128 + peer * 64 + lane],
                                 __ATOMIC_RELAXED, __HIP_MEMORY_SCOPE_AGENT);
      hbufd[cur + (dr >> 5) * 40 + (dr & 31)] = d;
    }
    __syncthreads();

    // x-projection for unit u (redundant across the quad's 4 lanes).
    const float* xpt = xp + (size_t)t * H3 + u;
    float xr = xpt[0], xz = xpt[HN], xn = xpt[2 * HN];

    // Matvec: 3 rows x one 64-k chunk per lane (96 fdot2).
    const uint* hb = &hbufd[cur + kc * 40];
    float a0 = 0.f, a1 = 0.f, a2 = 0.f;
#pragma unroll
    for (int qq = 0; qq < 8; ++qq) {
      uint4 v = *(const uint4*)&hb[qq * 4];
      uint hv[4] = {v.x, v.y, v.z, v.w};
#pragma unroll
      for (int p = 0; p < 4; ++p) {
        h2 hp = __builtin_bit_cast(h2, hv[p]);
        a0 = fdot2(wreg[0][qq * 4 + p], hp, a0);
        a1 = fdot2(wreg[1][qq * 4 + p], hp, a1);
        a2 = fdot2(wreg[2][qq * 4 + p], hp, a2);
      }
    }
    // Quad butterfly: all 4 lanes end with the full, bit-identical k-sum.
    a0 += dpp_qperm<0xB1>(a0); a0 += dpp_qperm<0x4E>(a0);
    a1 += dpp_qperm<0xB1>(a1); a1 += dpp_qperm<0x4E>(a1);
    a2 += dpp_qperm<0xB1>(a2); a2 += dpp_qperm<0x4E>(a2);

    // Gates (args pre-scaled by log2e / 2log2e).
    float r = fast_rcp(1.f + fast_exp2(-(xr + a0)));
    float z = fast_rcp(1.f + fast_exp2(-(xz + a1)));
    float nv = fmaf(2.f, fast_rcp(1.f + fast_exp2(-fmaf(r, a2 + bhn, xn))), -1.f);
    hj = fmaf(z, hj - nv, nv);

    // Publish h_{t+1} into buf[nxt] + slot parity (t+1)&1. Lanes L and L+4
    // ((lane&7)==0) are the kc==0 lanes of adjacent quads -> one dword/pair.
    float hj4 = __shfl(hj, lane + 4);  // all lanes execute (uniform path)
    if ((lane & 7) == 0) {
      h2 pv = h2{(_Float16)hj, (_Float16)hj4};
      uint pw = __builtin_bit_cast(uint, pv);
      const int ld = wv * 8 + (lane >> 3);   // local dword 0..63
      const int dg = 64 * b + ld;            // global h-dword index
      hbufd[nxt + (dg >> 5) * 40 + (dg & 31)] = pw;
      __hip_atomic_store(&slots[((t + 1) & 1) * 128 + b * 64 + ld], pw,
                         __ATOMIC_RELAXED, __HIP_MEMORY_SCOPE_AGENT);
      if (hs_out) *(float2*)&hs_out[(size_t)t * HN + u] = make_float2(hj, hj4);
    }
    __syncthreads();  // drains vmcnt (slot stores done) + orders LDS h
    if (tid == 0)
      __hip_atomic_store(myflag, (uint)(t + 2), __ATOMIC_RELEASE,
                         __HIP_MEMORY_SCOPE_AGENT);
  }
  // Tail: shfl hoisted out of the divergent branch (r12 bug #2).
  float hj4t = __shfl(hj, lane + 4);
  if (hT_out && (lane & 7) == 0)
    *(float2*)&hT_out[u] = make_float2(hj, hj4t);
}

// Decoder scan pair (standalone, 2 blocks).
__global__ __launch_bounds__(512) void gru_pair(
    const float* __restrict__ xp, const float* __restrict__ Whh,
    const float* __restrict__ bhh, const float* __restrict__ h0,
    float* __restrict__ hs_out, float* __restrict__ hT_out,
    uint* __restrict__ slots, uint* __restrict__ flags) {
  __shared__ __align__(16) uint hbufd[2 * 160];
  gru_scan2(blockIdx.x, xp, Whh, bhh, h0, hs_out, hT_out, slots, flags, hbufd);
}

// Encoder scan pair (blocks 0,1) + xpd projection (blocks 2..385).
// The GEMM blocks free-run (no communication with the scan) -> safe.
__global__ __launch_bounds__(512) void fused_enc(
    const float* __restrict__ xpe, const float* __restrict__ Whh_e,
    const float* __restrict__ bhh_e, float* __restrict__ henc,
    uint* __restrict__ slots, uint* __restrict__ flags,
    const float* __restrict__ x, const _Float16* __restrict__ wdh,
    const float* __restrict__ bih_d, const float* __restrict__ bhh_d,
    float* __restrict__ xpd) {
  __shared__ __align__(16) uint hbufd[2 * 160];
  __shared__ _Float16 As[64][40];
  __shared__ _Float16 Bs[64][40];
  if (blockIdx.x < 2) {
    gru_scan2(blockIdx.x, xpe, Whh_e, bhh_e, nullptr, nullptr, henc,
              slots, flags, hbufd);
  } else {
    const int bb = blockIdx.x - 2;  // 0..383
    gemm16_tile(threadIdx.x & 255, bb % 12, bb / 12, x, II, wdh, H3, IIP,
                bih_d, bhh_d, 2 * HN, L2E, 2.f * L2E, 2 * HN, xpd, As, Bs);
  }
}

extern "C" void kernel_launch(void* const* d_in, const int* in_sizes, int n_in,
                              void* d_out, int out_size, void* d_ws, size_t ws_size,
                              hipStream_t stream) {
  const float* x     = (const float*)d_in[0];   // [1, 2048, 1739]
  const float* Wih_e = (const float*)d_in[2];   // [768, 1739]
  const float* Whh_e = (const float*)d_in[3];   // [768, 256]
  const float* bih_e = (const float*)d_in[4];   // [768]
  const float* bhh_e = (const float*)d_in[5];   // [768]
  const float* Wih_d = (const float*)d_in[6];
  const float* Whh_d = (const float*)d_in[7];
  const float* bih_d = (const float*)d_in[8];
  const float* bhh_d = (const float*)d_in[9];
  const float* Wout  = (const float*)d_in[10];  // [1739, 256]
  const float* bout  = (const float*)d_in[11];  // [1739]
  float* out = (float*)d_out;                   // [2048, 1, 1739]

  // Workspace layout:
  float* ws = (float*)d_ws;
  float* xpe  = ws;                              // 2048*768
  float* xpd  = xpe + (size_t)TT * H3;           // 2048*768
  float* hs   = xpd + (size_t)TT * H3;           // 2048*256
  float* henc = hs + (size_t)TT * HN;            // 256
  _Float16* weh = (_Float16*)(henc + HN);        // [768][1760] f16
  _Float16* wdh = weh + (size_t)768 * IIP;       // [768][1760] f16
  _Float16* woh = wdh + (size_t)768 * IIP;       // [1739][256] f16
  uint* sync = (uint*)(woh + (size_t)II * HN);   // sync area
  uint* slots_e = sync;                          // [2][2][64] dwords
  uint* slots_d = sync + 256;                    // [2][2][64] dwords
  uint* flags   = sync + 512;                    // 256 dwords (e0,e1,d0,d1 @ 0,64,128,192)

  // Zero all four flag lines each launch (graph-capture-safe).
  hipMemsetAsync(flags, 0, 256 * sizeof(uint), stream);

  // One-time weight conversion to f16.
  prep_f16<<<dim3(1024), dim3(256), 0, stream>>>(Wih_e, Wih_d, Wout,
                                                 weh, wdh, woh);
  // g1: xpe projection (pre-scaled for exp2 gates: r,z rows by log2e,
  // n rows by 2log2e; bhh folded for r,z).
  gemm16<<<dim3(12, 32), dim3(256), 0, stream>>>(x, II, weh, H3, IIP,
      bih_e, bhh_e, 2 * HN, L2E, 2.f * L2E, 2 * HN, xpe);
  // Encoder scan pair (blocks 0,1) || xpd projection (blocks 2..385).
  fused_enc<<<dim3(386), dim3(512), 0, stream>>>(xpe, Whh_e, bhh_e, henc,
      slots_e, flags, x, wdh, bih_d, bhh_d, xpd);
  // Decoder scan pair -> hs.
  gru_pair<<<dim3(2), dim3(512), 0, stream>>>(xpd, Whh_d, bhh_d, henc,
      hs, nullptr, slots_d, flags + 128);
  // g3: output projection.
  gemm16<<<dim3(28, 32), dim3(256), 0, stream>>>(hs, HN, woh, II, HN,
      bout, nullptr, 0, 1.f, 1.f, 0, out);
}